// Round 1
// baseline (413.641 us; speedup 1.0000x reference)
//
#include <hip/hip_runtime.h>
#include <cstdint>
#include <cstddef>

// Problem constants (from reference)
#define N_NODES 20000
#define N_EDGES 320000
#define IN_DIM  256
#define HID     128     // layer0 per-head feat
#define OUT_DIM 64      // layer1 feat
#define H0      4       // layer0 heads

static __device__ __forceinline__ float leaky(float x) { return x > 0.f ? x : 0.2f * x; }

// ---------------- CSR build ----------------
__global__ void zero_i32(int* __restrict__ p, int n) {
  int i = blockIdx.x * 256 + threadIdx.x;
  if (i < n) p[i] = 0;
}

__global__ void hist_kernel(const int* __restrict__ dst, int* __restrict__ cnt) {
  int e = blockIdx.x * 256 + threadIdx.x;
  if (e < N_EDGES) atomicAdd(&cnt[dst[e]], 1);
}

// single-block exclusive scan over N_NODES counts -> rowstart[N_NODES+1]
__global__ void scan_kernel(const int* __restrict__ cnt, int* __restrict__ rowstart) {
  __shared__ int sdata[1024];
  __shared__ int carry_s;
  if (threadIdx.x == 0) carry_s = 0;
  __syncthreads();
  for (int base = 0; base < N_NODES; base += 1024) {
    int i = base + (int)threadIdx.x;
    int v = (i < N_NODES) ? cnt[i] : 0;
    sdata[threadIdx.x] = v;
    __syncthreads();
    for (int off = 1; off < 1024; off <<= 1) {
      int t = (threadIdx.x >= off) ? sdata[threadIdx.x - off] : 0;
      __syncthreads();
      sdata[threadIdx.x] += t;
      __syncthreads();
    }
    if (i < N_NODES) rowstart[i] = carry_s + sdata[threadIdx.x] - v;  // exclusive
    int total = sdata[1023];
    __syncthreads();
    if (threadIdx.x == 0) carry_s += total;
    __syncthreads();
  }
  if (threadIdx.x == 0) rowstart[N_NODES] = carry_s;
}

__global__ void fill_kernel(const int* __restrict__ src, const int* __restrict__ dst,
                            const int* __restrict__ rowstart, int* __restrict__ fill,
                            int* __restrict__ csr_src) {
  int e = blockIdx.x * 256 + threadIdx.x;
  if (e < N_EDGES) {
    int d = dst[e];
    int p = atomicAdd(&fill[d], 1);
    csr_src[rowstart[d] + p] = src[e];
  }
}

// ---------------- fp32 tiled GEMM: C[M,N] = A[M,K] @ B[K,N] ----------------
// BM=BN=64, BK=16, 256 threads, 4x4 micro-tile per thread.
__global__ __launch_bounds__(256) void gemm_kernel(const float* __restrict__ A,
                                                   const float* __restrict__ B,
                                                   float* __restrict__ C,
                                                   int M, int N, int K) {
  __shared__ float As[16][64];
  __shared__ float Bs[16][64];
  int tid  = threadIdx.x;
  int row0 = blockIdx.y * 64;
  int col0 = blockIdx.x * 64;
  int tcol = (tid & 15) * 4;
  int trow = (tid >> 4) * 4;
  int a_m  = tid >> 2;          // 0..63
  int a_k  = (tid & 3) * 4;     // 0,4,8,12
  int b_k  = tid >> 4;          // 0..15
  int b_n  = (tid & 15) * 4;    // 0..60
  float acc[4][4] = {};
  for (int k0 = 0; k0 < K; k0 += 16) {
    float4 av = make_float4(0.f, 0.f, 0.f, 0.f);
    int arow = row0 + a_m;
    if (arow < M) av = *(const float4*)&A[(size_t)arow * K + k0 + a_k];
    As[a_k + 0][a_m] = av.x;
    As[a_k + 1][a_m] = av.y;
    As[a_k + 2][a_m] = av.z;
    As[a_k + 3][a_m] = av.w;
    *(float4*)&Bs[b_k][b_n] = *(const float4*)&B[(size_t)(k0 + b_k) * N + col0 + b_n];
    __syncthreads();
#pragma unroll
    for (int kk = 0; kk < 16; kk++) {
      float a[4], b[4];
#pragma unroll
      for (int i = 0; i < 4; i++) { a[i] = As[kk][trow + i]; }
#pragma unroll
      for (int j = 0; j < 4; j++) { b[j] = Bs[kk][tcol + j]; }
#pragma unroll
      for (int i = 0; i < 4; i++) {
#pragma unroll
        for (int j = 0; j < 4; j++) { acc[i][j] += a[i] * b[j]; }
      }
    }
    __syncthreads();
  }
#pragma unroll
  for (int i = 0; i < 4; i++) {
    int r = row0 + trow + i;
    if (r < M) {
#pragma unroll
      for (int j = 0; j < 4; j++) {
        C[(size_t)r * N + col0 + tcol + j] = acc[i][j];
      }
    }
  }
}

// ---------------- attention coefficients: el/er = sum_d feat*a ----------------
// one wave per (n,h); D in {64,128} (per-lane elems = D/64)
__global__ void coef_kernel(const float* __restrict__ feat, const float* __restrict__ al,
                            const float* __restrict__ ar, float* __restrict__ el,
                            float* __restrict__ er, int H, int D) {
  int w = blockIdx.x * 4 + (threadIdx.x >> 6);
  int lane = threadIdx.x & 63;
  if (w >= N_NODES * H) return;
  int n = w / H, h = w % H;
  int per = D >> 6;
  const float* f   = feat + (size_t)n * H * D + (size_t)h * D;
  const float* alh = al + h * D;
  const float* arh = ar + h * D;
  float sl = 0.f, sr = 0.f;
  for (int i = 0; i < per; i++) {
    int d = lane + 64 * i;
    float fv = f[d];
    sl += fv * alh[d];
    sr += fv * arh[d];
  }
  for (int off = 32; off; off >>= 1) {
    sl += __shfl_xor(sl, off);
    sr += __shfl_xor(sr, off);
  }
  if (lane == 0) { el[w] = sl; er[w] = sr; }
}

// ---------------- layer0 aggregation: per node, 4 waves = 4 heads ----------------
// out = ELU( sum_e alpha_e * feat1[src_e, h, :] + b1 ), written as h1[n, 512]
__global__ __launch_bounds__(256) void agg0_kernel(const int* __restrict__ rowstart,
                                                   const int* __restrict__ csr_src,
                                                   const float* __restrict__ el,
                                                   const float* __restrict__ er,
                                                   const float* __restrict__ feat,
                                                   const float* __restrict__ bias,
                                                   float* __restrict__ out) {
  int n = blockIdx.x;
  int h = threadIdx.x >> 6;
  int lane = threadIdx.x & 63;
  int start = rowstart[n];
  int deg = rowstart[n + 1] - start;
  float erd = er[n * H0 + h];
  float m = -1e30f;
  for (int i = lane; i < deg; i += 64) {
    int s = csr_src[start + i];
    m = fmaxf(m, leaky(el[s * H0 + h] + erd));
  }
  for (int off = 32; off; off >>= 1) m = fmaxf(m, __shfl_xor(m, off));
  float ssum = 0.f;
  for (int i = lane; i < deg; i += 64) {
    int s = csr_src[start + i];
    ssum += __expf(leaky(el[s * H0 + h] + erd) - m);
  }
  for (int off = 32; off; off >>= 1) ssum += __shfl_xor(ssum, off);
  float inv = (deg > 0) ? 1.f / ssum : 0.f;
  float accx = 0.f, accy = 0.f;
  for (int i = 0; i < deg; i++) {
    int s = csr_src[start + i];                 // wave-uniform broadcast load
    float a = __expf(leaky(el[s * H0 + h] + erd) - m) * inv;
    const float2 f = *(const float2*)&feat[(size_t)s * (H0 * HID) + h * HID + 2 * lane];
    accx += a * f.x;
    accy += a * f.y;
  }
  int d0 = 2 * lane;
  float o0 = accx + bias[h * HID + d0];
  float o1 = accy + bias[h * HID + d0 + 1];
  o0 = o0 > 0.f ? o0 : (__expf(o0) - 1.f);   // ELU
  o1 = o1 > 0.f ? o1 : (__expf(o1) - 1.f);
  out[(size_t)n * (H0 * HID) + h * HID + d0]     = o0;
  out[(size_t)n * (H0 * HID) + h * HID + d0 + 1] = o1;
}

// ---------------- layer1 aggregation: one wave per node, D=64 ----------------
__global__ __launch_bounds__(64) void agg1_kernel(const int* __restrict__ rowstart,
                                                  const int* __restrict__ csr_src,
                                                  const float* __restrict__ el,
                                                  const float* __restrict__ er,
                                                  const float* __restrict__ feat,
                                                  const float* __restrict__ bias,
                                                  float* __restrict__ out) {
  int n = blockIdx.x;
  int lane = threadIdx.x;
  int start = rowstart[n];
  int deg = rowstart[n + 1] - start;
  float erd = er[n];
  float m = -1e30f;
  for (int i = lane; i < deg; i += 64) {
    m = fmaxf(m, leaky(el[csr_src[start + i]] + erd));
  }
  for (int off = 32; off; off >>= 1) m = fmaxf(m, __shfl_xor(m, off));
  float ssum = 0.f;
  for (int i = lane; i < deg; i += 64) {
    ssum += __expf(leaky(el[csr_src[start + i]] + erd) - m);
  }
  for (int off = 32; off; off >>= 1) ssum += __shfl_xor(ssum, off);
  float inv = (deg > 0) ? 1.f / ssum : 0.f;
  float acc = 0.f;
  for (int i = 0; i < deg; i++) {
    int s = csr_src[start + i];
    float a = __expf(leaky(el[s] + erd) - m) * inv;
    acc += a * feat[(size_t)s * OUT_DIM + lane];
  }
  out[(size_t)n * OUT_DIM + lane] = acc + bias[lane];
}

extern "C" void kernel_launch(void* const* d_in, const int* in_sizes, int n_in,
                              void* d_out, int out_size, void* d_ws, size_t ws_size,
                              hipStream_t stream) {
  const float* x   = (const float*)d_in[0];
  const int*   src = (const int*)d_in[1];
  const int*   dst = (const int*)d_in[2];
  const float* W1  = (const float*)d_in[3];
  const float* al1 = (const float*)d_in[4];
  const float* ar1 = (const float*)d_in[5];
  const float* b1  = (const float*)d_in[6];
  const float* W2  = (const float*)d_in[7];
  const float* al2 = (const float*)d_in[8];
  const float* ar2 = (const float*)d_in[9];
  const float* b2  = (const float*)d_in[10];

  char* ws = (char*)d_ws;
  size_t off = 0;
  auto alloc = [&](size_t bytes) -> void* {
    void* p = ws + off;
    off += (bytes + 255) & ~(size_t)255;
    return p;
  };
  int* cnt      = (int*)alloc((size_t)2 * N_NODES * 4);  // cnt + fill contiguous
  int* fill     = cnt + N_NODES;
  int* rowstart = (int*)alloc((size_t)(N_NODES + 1) * 4);
  int* csr_src  = (int*)alloc((size_t)N_EDGES * 4);
  float* feat1  = (float*)alloc((size_t)N_NODES * (H0 * HID) * 4);
  float* el1    = (float*)alloc((size_t)N_NODES * H0 * 4);
  float* er1    = (float*)alloc((size_t)N_NODES * H0 * 4);
  float* h1     = (float*)alloc((size_t)N_NODES * (H0 * HID) * 4);
  float* feat2  = (float*)alloc((size_t)N_NODES * OUT_DIM * 4);
  float* el2    = (float*)alloc((size_t)N_NODES * 4);
  float* er2    = (float*)alloc((size_t)N_NODES * 4);
  (void)ws_size; (void)in_sizes; (void)n_in; (void)out_size;

  // 1) CSR build (shared by both layers)
  zero_i32<<<(2 * N_NODES + 255) / 256, 256, 0, stream>>>(cnt, 2 * N_NODES);
  hist_kernel<<<(N_EDGES + 255) / 256, 256, 0, stream>>>(dst, cnt);
  scan_kernel<<<1, 1024, 0, stream>>>(cnt, rowstart);
  fill_kernel<<<(N_EDGES + 255) / 256, 256, 0, stream>>>(src, dst, rowstart, fill, csr_src);

  // 2) layer 0
  {
    dim3 g((H0 * HID) / 64, (N_NODES + 63) / 64);
    gemm_kernel<<<g, 256, 0, stream>>>(x, W1, feat1, N_NODES, H0 * HID, IN_DIM);
  }
  coef_kernel<<<(N_NODES * H0 + 3) / 4, 256, 0, stream>>>(feat1, al1, ar1, el1, er1, H0, HID);
  agg0_kernel<<<N_NODES, 256, 0, stream>>>(rowstart, csr_src, el1, er1, feat1, b1, h1);

  // 3) layer 1
  {
    dim3 g(OUT_DIM / 64, (N_NODES + 63) / 64);
    gemm_kernel<<<g, 256, 0, stream>>>(h1, W2, feat2, N_NODES, OUT_DIM, H0 * HID);
  }
  coef_kernel<<<(N_NODES + 3) / 4, 256, 0, stream>>>(feat2, al2, ar2, el2, er2, 1, OUT_DIM);
  agg1_kernel<<<N_NODES, 64, 0, stream>>>(rowstart, csr_src, el2, er2, feat2, b2, (float*)d_out);
}

// Round 3
// 366.499 us; speedup vs baseline: 1.1286x; 1.1286x over previous
//
#include <hip/hip_runtime.h>
#include <hip/hip_bf16.h>
#include <cstdint>
#include <cstddef>

// Problem constants (from reference)
#define N_NODES 20000
#define N_EDGES 320000
#define IN_DIM  256
#define HID     128     // layer0 per-head feat
#define OUT_DIM 64      // layer1 feat
#define H0      4       // layer0 heads

static __device__ __forceinline__ float leaky(float x) { return x > 0.f ? x : 0.2f * x; }

// ---------------- CSR build ----------------
__global__ void zero_i32(int* __restrict__ p, int n) {
  int i = blockIdx.x * 256 + threadIdx.x;
  if (i < n) p[i] = 0;
}

__global__ void hist_kernel(const int* __restrict__ dst, int* __restrict__ cnt) {
  int e = blockIdx.x * 256 + threadIdx.x;
  if (e < N_EDGES) atomicAdd(&cnt[dst[e]], 1);
}

// single-block exclusive scan over N_NODES counts -> rowstart[N_NODES+1]
__global__ void scan_kernel(const int* __restrict__ cnt, int* __restrict__ rowstart) {
  __shared__ int sdata[1024];
  __shared__ int carry_s;
  if (threadIdx.x == 0) carry_s = 0;
  __syncthreads();
  for (int base = 0; base < N_NODES; base += 1024) {
    int i = base + (int)threadIdx.x;
    int v = (i < N_NODES) ? cnt[i] : 0;
    sdata[threadIdx.x] = v;
    __syncthreads();
    for (int off = 1; off < 1024; off <<= 1) {
      int t = (threadIdx.x >= off) ? sdata[threadIdx.x - off] : 0;
      __syncthreads();
      sdata[threadIdx.x] += t;
      __syncthreads();
    }
    if (i < N_NODES) rowstart[i] = carry_s + sdata[threadIdx.x] - v;  // exclusive
    int total = sdata[1023];
    __syncthreads();
    if (threadIdx.x == 0) carry_s += total;
    __syncthreads();
  }
  if (threadIdx.x == 0) rowstart[N_NODES] = carry_s;
}

__global__ void fill_kernel(const int* __restrict__ src, const int* __restrict__ dst,
                            const int* __restrict__ rowstart, int* __restrict__ fill,
                            int* __restrict__ csr_src) {
  int e = blockIdx.x * 256 + threadIdx.x;
  if (e < N_EDGES) {
    int d = dst[e];
    int p = atomicAdd(&fill[d], 1);
    csr_src[rowstart[d] + p] = src[e];
  }
}

// ---------------- bf16x3 MFMA GEMM: C[M,N] = A[M,K] @ B[K,N] ----------------
// fp32 inputs are split in-kernel to bf16 hi+lo; C = Ah*Bh + Ah*Bl + Al*Bh
// (Al*Bl dropped: ~2^-18 relative). Tile BM=128 x BN x BK=32; 256 threads
// (4 waves as 2x2), 16x16x32 MFMA.
// Verified layouts (learn_hip m89/m120): A-frag A[m=lane&15][k=(lane>>4)*8+j];
// B-frag B[k=(lane>>4)*8+j][n=lane&15]; C/D col=lane&15, row=(lane>>4)*4+reg.

using short8  = __attribute__((ext_vector_type(8))) short;
using short4v = __attribute__((ext_vector_type(4))) short;
using f32x4   = __attribute__((ext_vector_type(4))) float;

#define LDK 40   // padded LDS k-stride (32 + 8), keeps 16B alignment for b128

struct HL { short h; short l; };
static __device__ __forceinline__ HL split_bf16(float x) {
  HL r;
  __hip_bfloat16 hb = __float2bfloat16(x);
  float hf = __bfloat162float(hb);
  __hip_bfloat16 lb = __float2bfloat16(x - hf);
  r.h = *(short*)&hb;
  r.l = *(short*)&lb;
  return r;
}

template <int BN>
__global__ __launch_bounds__(256) void gemm_mfma(const float* __restrict__ A,
                                                 const float* __restrict__ B,
                                                 float* __restrict__ C,
                                                 int M, int N, int K) {
  constexpr int NT = BN / 32;          // n-tiles of 16 per wave (2 or 4)
  __shared__ short Ash[128 * LDK];
  __shared__ short Asl[128 * LDK];
  __shared__ short Bsh[BN * LDK];
  __shared__ short Bsl[BN * LDK];
  const int tid  = threadIdx.x;
  const int lane = tid & 63;
  const int wave = tid >> 6;
  const int wm = (wave >> 1) * 64;     // wave m-offset: 0 or 64
  const int wn = (wave & 1) * (BN / 2);// wave n-offset
  const int row0 = blockIdx.y * 128;
  const int col0 = blockIdx.x * BN;
  const int lr = lane & 15;            // within-tile index
  const int lq = lane >> 4;            // quad
  // staging maps
  const int ar = tid >> 1;             // A row 0..127
  const int ak = (tid & 1) * 16;       // A k base (0 or 16)
  const int bk = tid & 31;             // B k 0..31
  const int bn = (tid >> 5) * (BN / 8);// B n base

  f32x4 acc[4][NT];
#pragma unroll
  for (int i = 0; i < 4; i++)
#pragma unroll
    for (int j = 0; j < NT; j++) acc[i][j] = (f32x4){0.f, 0.f, 0.f, 0.f};

  for (int k0 = 0; k0 < K; k0 += 32) {
    // --- stage A (128x32 fp32 -> bf16 hi/lo) ---
    {
      const float* Ag = A + (size_t)(row0 + ar) * K + k0 + ak;
      const bool ok = (row0 + ar) < M;
#pragma unroll
      for (int i = 0; i < 4; i++) {
        float4 v = ok ? *(const float4*)(Ag + 4 * i) : make_float4(0.f, 0.f, 0.f, 0.f);
        HL e0 = split_bf16(v.x), e1 = split_bf16(v.y), e2 = split_bf16(v.z), e3 = split_bf16(v.w);
        short4v hv, lv;
        hv[0] = e0.h; hv[1] = e1.h; hv[2] = e2.h; hv[3] = e3.h;
        lv[0] = e0.l; lv[1] = e1.l; lv[2] = e2.l; lv[3] = e3.l;
        *(short4v*)&Ash[ar * LDK + ak + 4 * i] = hv;
        *(short4v*)&Asl[ar * LDK + ak + 4 * i] = lv;
      }
    }
    // --- stage B (32xBN fp32 -> bf16 hi/lo, transposed to [n][k]) ---
    {
      const float* Bg = B + (size_t)(k0 + bk) * N + col0 + bn;
#pragma unroll
      for (int i = 0; i < BN / 32; i++) {
        float4 v = *(const float4*)(Bg + 4 * i);
        HL e0 = split_bf16(v.x), e1 = split_bf16(v.y), e2 = split_bf16(v.z), e3 = split_bf16(v.w);
        Bsh[(bn + 4 * i + 0) * LDK + bk] = e0.h; Bsl[(bn + 4 * i + 0) * LDK + bk] = e0.l;
        Bsh[(bn + 4 * i + 1) * LDK + bk] = e1.h; Bsl[(bn + 4 * i + 1) * LDK + bk] = e1.l;
        Bsh[(bn + 4 * i + 2) * LDK + bk] = e2.h; Bsl[(bn + 4 * i + 2) * LDK + bk] = e2.l;
        Bsh[(bn + 4 * i + 3) * LDK + bk] = e3.h; Bsl[(bn + 4 * i + 3) * LDK + bk] = e3.l;
      }
    }
    __syncthreads();
    // --- fragments ---
    short8 a_h[4], a_l[4], b_h[NT], b_l[NT];
#pragma unroll
    for (int mi = 0; mi < 4; mi++) {
      int r = wm + mi * 16 + lr;
      a_h[mi] = *(const short8*)&Ash[r * LDK + lq * 8];
      a_l[mi] = *(const short8*)&Asl[r * LDK + lq * 8];
    }
#pragma unroll
    for (int nj = 0; nj < NT; nj++) {
      int c = wn + nj * 16 + lr;
      b_h[nj] = *(const short8*)&Bsh[c * LDK + lq * 8];
      b_l[nj] = *(const short8*)&Bsl[c * LDK + lq * 8];
    }
    // --- 3-term MFMA ---
#pragma unroll
    for (int mi = 0; mi < 4; mi++) {
#pragma unroll
      for (int nj = 0; nj < NT; nj++) {
        acc[mi][nj] = __builtin_amdgcn_mfma_f32_16x16x32_bf16(a_h[mi], b_l[nj], acc[mi][nj], 0, 0, 0);
        acc[mi][nj] = __builtin_amdgcn_mfma_f32_16x16x32_bf16(a_l[mi], b_h[nj], acc[mi][nj], 0, 0, 0);
        acc[mi][nj] = __builtin_amdgcn_mfma_f32_16x16x32_bf16(a_h[mi], b_h[nj], acc[mi][nj], 0, 0, 0);
      }
    }
    __syncthreads();
  }
  // --- epilogue ---
#pragma unroll
  for (int mi = 0; mi < 4; mi++) {
#pragma unroll
    for (int r = 0; r < 4; r++) {
      int row = row0 + wm + mi * 16 + lq * 4 + r;
      if (row < M) {
#pragma unroll
        for (int nj = 0; nj < NT; nj++) {
          C[(size_t)row * N + col0 + wn + nj * 16 + lr] = acc[mi][nj][r];
        }
      }
    }
  }
}

// ---------------- attention coefficients: el/er = sum_d feat*a ----------------
// one wave per (n,h); D in {64,128} (per-lane elems = D/64)
__global__ void coef_kernel(const float* __restrict__ feat, const float* __restrict__ al,
                            const float* __restrict__ ar, float* __restrict__ el,
                            float* __restrict__ er, int H, int D) {
  int w = blockIdx.x * 4 + (threadIdx.x >> 6);
  int lane = threadIdx.x & 63;
  if (w >= N_NODES * H) return;
  int n = w / H, h = w % H;
  int per = D >> 6;
  const float* f   = feat + (size_t)n * H * D + (size_t)h * D;
  const float* alh = al + h * D;
  const float* arh = ar + h * D;
  float sl = 0.f, sr = 0.f;
  for (int i = 0; i < per; i++) {
    int d = lane + 64 * i;
    float fv = f[d];
    sl += fv * alh[d];
    sr += fv * arh[d];
  }
  for (int off = 32; off; off >>= 1) {
    sl += __shfl_xor(sl, off);
    sr += __shfl_xor(sr, off);
  }
  if (lane == 0) { el[w] = sl; er[w] = sr; }
}

// ---------------- layer0 aggregation: per node, 4 waves = 4 heads ----------------
__global__ __launch_bounds__(256) void agg0_kernel(const int* __restrict__ rowstart,
                                                   const int* __restrict__ csr_src,
                                                   const float* __restrict__ el,
                                                   const float* __restrict__ er,
                                                   const float* __restrict__ feat,
                                                   const float* __restrict__ bias,
                                                   float* __restrict__ out) {
  int n = blockIdx.x;
  int h = threadIdx.x >> 6;
  int lane = threadIdx.x & 63;
  int start = rowstart[n];
  int deg = rowstart[n + 1] - start;
  float erd = er[n * H0 + h];
  float m = -1e30f;
  for (int i = lane; i < deg; i += 64) {
    int s = csr_src[start + i];
    m = fmaxf(m, leaky(el[s * H0 + h] + erd));
  }
  for (int off = 32; off; off >>= 1) m = fmaxf(m, __shfl_xor(m, off));
  float ssum = 0.f;
  for (int i = lane; i < deg; i += 64) {
    int s = csr_src[start + i];
    ssum += __expf(leaky(el[s * H0 + h] + erd) - m);
  }
  for (int off = 32; off; off >>= 1) ssum += __shfl_xor(ssum, off);
  float inv = (deg > 0) ? 1.f / ssum : 0.f;
  float accx = 0.f, accy = 0.f;
  for (int i = 0; i < deg; i++) {
    int s = csr_src[start + i];                 // wave-uniform broadcast load
    float a = __expf(leaky(el[s * H0 + h] + erd) - m) * inv;
    const float2 f = *(const float2*)&feat[(size_t)s * (H0 * HID) + h * HID + 2 * lane];
    accx += a * f.x;
    accy += a * f.y;
  }
  int d0 = 2 * lane;
  float o0 = accx + bias[h * HID + d0];
  float o1 = accy + bias[h * HID + d0 + 1];
  o0 = o0 > 0.f ? o0 : (__expf(o0) - 1.f);   // ELU
  o1 = o1 > 0.f ? o1 : (__expf(o1) - 1.f);
  out[(size_t)n * (H0 * HID) + h * HID + d0]     = o0;
  out[(size_t)n * (H0 * HID) + h * HID + d0 + 1] = o1;
}

// ---------------- layer1 aggregation: one wave per node, D=64 ----------------
__global__ __launch_bounds__(64) void agg1_kernel(const int* __restrict__ rowstart,
                                                  const int* __restrict__ csr_src,
                                                  const float* __restrict__ el,
                                                  const float* __restrict__ er,
                                                  const float* __restrict__ feat,
                                                  const float* __restrict__ bias,
                                                  float* __restrict__ out) {
  int n = blockIdx.x;
  int lane = threadIdx.x;
  int start = rowstart[n];
  int deg = rowstart[n + 1] - start;
  float erd = er[n];
  float m = -1e30f;
  for (int i = lane; i < deg; i += 64) {
    m = fmaxf(m, leaky(el[csr_src[start + i]] + erd));
  }
  for (int off = 32; off; off >>= 1) m = fmaxf(m, __shfl_xor(m, off));
  float ssum = 0.f;
  for (int i = lane; i < deg; i += 64) {
    ssum += __expf(leaky(el[csr_src[start + i]] + erd) - m);
  }
  for (int off = 32; off; off >>= 1) ssum += __shfl_xor(ssum, off);
  float inv = (deg > 0) ? 1.f / ssum : 0.f;
  float acc = 0.f;
  for (int i = 0; i < deg; i++) {
    int s = csr_src[start + i];
    float a = __expf(leaky(el[s] + erd) - m) * inv;
    acc += a * feat[(size_t)s * OUT_DIM + lane];
  }
  out[(size_t)n * OUT_DIM + lane] = acc + bias[lane];
}

extern "C" void kernel_launch(void* const* d_in, const int* in_sizes, int n_in,
                              void* d_out, int out_size, void* d_ws, size_t ws_size,
                              hipStream_t stream) {
  const float* x   = (const float*)d_in[0];
  const int*   src = (const int*)d_in[1];
  const int*   dst = (const int*)d_in[2];
  const float* W1  = (const float*)d_in[3];
  const float* al1 = (const float*)d_in[4];
  const float* ar1 = (const float*)d_in[5];
  const float* b1  = (const float*)d_in[6];
  const float* W2  = (const float*)d_in[7];
  const float* al2 = (const float*)d_in[8];
  const float* ar2 = (const float*)d_in[9];
  const float* b2  = (const float*)d_in[10];

  char* ws = (char*)d_ws;
  size_t off = 0;
  auto alloc = [&](size_t bytes) -> void* {
    void* p = ws + off;
    off += (bytes + 255) & ~(size_t)255;
    return p;
  };
  int* cnt      = (int*)alloc((size_t)2 * N_NODES * 4);  // cnt + fill contiguous
  int* fill     = cnt + N_NODES;
  int* rowstart = (int*)alloc((size_t)(N_NODES + 1) * 4);
  int* csr_src  = (int*)alloc((size_t)N_EDGES * 4);
  float* feat1  = (float*)alloc((size_t)N_NODES * (H0 * HID) * 4);
  float* el1    = (float*)alloc((size_t)N_NODES * H0 * 4);
  float* er1    = (float*)alloc((size_t)N_NODES * H0 * 4);
  float* h1     = (float*)alloc((size_t)N_NODES * (H0 * HID) * 4);
  float* feat2  = (float*)alloc((size_t)N_NODES * OUT_DIM * 4);
  float* el2    = (float*)alloc((size_t)N_NODES * 4);
  float* er2    = (float*)alloc((size_t)N_NODES * 4);
  (void)ws_size; (void)in_sizes; (void)n_in; (void)out_size;

  // 1) CSR build (shared by both layers)
  zero_i32<<<(2 * N_NODES + 255) / 256, 256, 0, stream>>>(cnt, 2 * N_NODES);
  hist_kernel<<<(N_EDGES + 255) / 256, 256, 0, stream>>>(dst, cnt);
  scan_kernel<<<1, 1024, 0, stream>>>(cnt, rowstart);
  fill_kernel<<<(N_EDGES + 255) / 256, 256, 0, stream>>>(src, dst, rowstart, fill, csr_src);

  // 2) layer 0: GEMM (bf16x3 MFMA), coef, aggregate
  {
    dim3 g((H0 * HID) / 128, (N_NODES + 127) / 128);
    gemm_mfma<128><<<g, 256, 0, stream>>>(x, W1, feat1, N_NODES, H0 * HID, IN_DIM);
  }
  coef_kernel<<<(N_NODES * H0 + 3) / 4, 256, 0, stream>>>(feat1, al1, ar1, el1, er1, H0, HID);
  agg0_kernel<<<N_NODES, 256, 0, stream>>>(rowstart, csr_src, el1, er1, feat1, b1, h1);

  // 3) layer 1
  {
    dim3 g(OUT_DIM / 64, (N_NODES + 127) / 128);
    gemm_mfma<64><<<g, 256, 0, stream>>>(h1, W2, feat2, N_NODES, OUT_DIM, H0 * HID);
  }
  coef_kernel<<<(N_NODES + 3) / 4, 256, 0, stream>>>(feat2, al2, ar2, el2, er2, 1, OUT_DIM);
  agg1_kernel<<<N_NODES, 64, 0, stream>>>(rowstart, csr_src, el2, er2, feat2, b2, (float*)d_out);
}

// Round 4
// 281.254 us; speedup vs baseline: 1.4707x; 1.3031x over previous
//
#include <hip/hip_runtime.h>
#include <hip/hip_bf16.h>
#include <cstdint>
#include <cstddef>

// Problem constants (from reference)
#define N_NODES 20000
#define N_EDGES 320000
#define IN_DIM  256
#define HID     128     // layer0 per-head feat
#define OUT_DIM 64      // layer1 feat
#define H0      4       // layer0 heads

static __device__ __forceinline__ float leaky(float x) { return x > 0.f ? x : 0.2f * x; }

// ---------------- CSR build ----------------
__global__ void zero_i32(int* __restrict__ p, int n) {
  int i = blockIdx.x * 256 + threadIdx.x;
  if (i < n) p[i] = 0;
}

__global__ void hist_kernel(const int* __restrict__ dst, int* __restrict__ cnt) {
  int e = blockIdx.x * 256 + threadIdx.x;
  if (e < N_EDGES) atomicAdd(&cnt[dst[e]], 1);
}

// single-block scan, 1024 threads, 20 elems/thread, 2 barriers total.
#define SCAN_PER 20
__global__ __launch_bounds__(1024) void scan_kernel(const int* __restrict__ cnt,
                                                    int* __restrict__ rowstart) {
  int t = threadIdx.x;
  int lane = t & 63, wid = t >> 6;
  int base = t * SCAN_PER;
  int loc[SCAN_PER];
  int s = 0;
  if (t < N_NODES / SCAN_PER) {
#pragma unroll
    for (int k = 0; k < SCAN_PER; k++) { loc[k] = cnt[base + k]; s += loc[k]; }
  }
  // inclusive wave scan of s
  int v = s;
#pragma unroll
  for (int off = 1; off < 64; off <<= 1) {
    int u = __shfl_up(v, off);
    if (lane >= off) v += u;
  }
  __shared__ int wsum[16];
  if (lane == 63) wsum[wid] = v;
  __syncthreads();
  if (t == 0) {
    int a = 0;
#pragma unroll
    for (int i = 0; i < 16; i++) { int x = wsum[i]; wsum[i] = a; a += x; }
    rowstart[N_NODES] = a;
  }
  __syncthreads();
  int excl = wsum[wid] + (v - s);   // exclusive prefix for this thread's chunk
  if (t < N_NODES / SCAN_PER) {
    int a = excl;
#pragma unroll
    for (int k = 0; k < SCAN_PER; k++) { rowstart[base + k] = a; a += loc[k]; }
  }
}

__global__ void fill_kernel(const int* __restrict__ src, const int* __restrict__ dst,
                            const int* __restrict__ rowstart, int* __restrict__ fill,
                            int* __restrict__ csr_src) {
  int e = blockIdx.x * 256 + threadIdx.x;
  if (e < N_EDGES) {
    int d = dst[e];
    int p = atomicAdd(&fill[d], 1);
    csr_src[rowstart[d] + p] = src[e];
  }
}

// ---------------- bf16x3 MFMA GEMM: C[M,N] = A[M,K] @ B[K,N] ----------------
// fp32 inputs split in-kernel to bf16 hi+lo; C = Ah*Bh + Ah*Bl + Al*Bh.
// Tile BM x BN x BK=32; 256 threads (4 waves as 2x2), 16x16x32 MFMA.
// Optionally also writes a bf16 copy of C (for downstream gather kernels).

using short8  = __attribute__((ext_vector_type(8))) short;
using short4v = __attribute__((ext_vector_type(4))) short;
using f32x4   = __attribute__((ext_vector_type(4))) float;

#define LDK 40   // padded LDS k-stride (32 + 8), keeps 16B alignment for b128

struct HL { short h; short l; };
static __device__ __forceinline__ HL split_bf16(float x) {
  HL r;
  __hip_bfloat16 hb = __float2bfloat16(x);
  float hf = __bfloat162float(hb);
  __hip_bfloat16 lb = __float2bfloat16(x - hf);
  r.h = *(short*)&hb;
  r.l = *(short*)&lb;
  return r;
}

template <int BM, int BN>
__global__ __launch_bounds__(256) void gemm_mfma(const float* __restrict__ A,
                                                 const float* __restrict__ B,
                                                 float* __restrict__ C,
                                                 __hip_bfloat16* __restrict__ Cb,
                                                 int M, int N, int K) {
  constexpr int MI = BM / 32;          // m-tiles of 16 per wave
  constexpr int NT = BN / 32;          // n-tiles of 16 per wave
  constexpr int TPR = 256 / BM;        // threads per A row
  constexpr int KPT = 32 / TPR;        // k elems per thread (16 or 8)
  __shared__ short Ash[BM * LDK];
  __shared__ short Asl[BM * LDK];
  __shared__ short Bsh[BN * LDK];
  __shared__ short Bsl[BN * LDK];
  const int tid  = threadIdx.x;
  const int lane = tid & 63;
  const int wave = tid >> 6;
  const int wm = (wave >> 1) * (BM / 2);
  const int wn = (wave & 1) * (BN / 2);
  const int row0 = blockIdx.y * BM;
  const int col0 = blockIdx.x * BN;
  const int lr = lane & 15;            // within-tile index
  const int lq = lane >> 4;            // quad
  // staging maps
  const int ar = tid / TPR;            // A row
  const int ak = (tid % TPR) * KPT;    // A k base
  const int bk = tid & 31;             // B k 0..31
  const int bn = (tid >> 5) * (BN / 8);// B n base

  f32x4 acc[MI][NT];
#pragma unroll
  for (int i = 0; i < MI; i++)
#pragma unroll
    for (int j = 0; j < NT; j++) acc[i][j] = (f32x4){0.f, 0.f, 0.f, 0.f};

  for (int k0 = 0; k0 < K; k0 += 32) {
    // --- stage A (BMx32 fp32 -> bf16 hi/lo) ---
    {
      const float* Ag = A + (size_t)(row0 + ar) * K + k0 + ak;
      const bool ok = (row0 + ar) < M;
#pragma unroll
      for (int i = 0; i < KPT / 4; i++) {
        float4 v = ok ? *(const float4*)(Ag + 4 * i) : make_float4(0.f, 0.f, 0.f, 0.f);
        HL e0 = split_bf16(v.x), e1 = split_bf16(v.y), e2 = split_bf16(v.z), e3 = split_bf16(v.w);
        short4v hv, lv;
        hv[0] = e0.h; hv[1] = e1.h; hv[2] = e2.h; hv[3] = e3.h;
        lv[0] = e0.l; lv[1] = e1.l; lv[2] = e2.l; lv[3] = e3.l;
        *(short4v*)&Ash[ar * LDK + ak + 4 * i] = hv;
        *(short4v*)&Asl[ar * LDK + ak + 4 * i] = lv;
      }
    }
    // --- stage B (32xBN fp32 -> bf16 hi/lo, transposed to [n][k]) ---
    {
      const float* Bg = B + (size_t)(k0 + bk) * N + col0 + bn;
#pragma unroll
      for (int i = 0; i < BN / 32; i++) {
        float4 v = *(const float4*)(Bg + 4 * i);
        HL e0 = split_bf16(v.x), e1 = split_bf16(v.y), e2 = split_bf16(v.z), e3 = split_bf16(v.w);
        Bsh[(bn + 4 * i + 0) * LDK + bk] = e0.h; Bsl[(bn + 4 * i + 0) * LDK + bk] = e0.l;
        Bsh[(bn + 4 * i + 1) * LDK + bk] = e1.h; Bsl[(bn + 4 * i + 1) * LDK + bk] = e1.l;
        Bsh[(bn + 4 * i + 2) * LDK + bk] = e2.h; Bsl[(bn + 4 * i + 2) * LDK + bk] = e2.l;
        Bsh[(bn + 4 * i + 3) * LDK + bk] = e3.h; Bsl[(bn + 4 * i + 3) * LDK + bk] = e3.l;
      }
    }
    __syncthreads();
    // --- fragments ---
    short8 a_h[MI], a_l[MI], b_h[NT], b_l[NT];
#pragma unroll
    for (int mi = 0; mi < MI; mi++) {
      int r = wm + mi * 16 + lr;
      a_h[mi] = *(const short8*)&Ash[r * LDK + lq * 8];
      a_l[mi] = *(const short8*)&Asl[r * LDK + lq * 8];
    }
#pragma unroll
    for (int nj = 0; nj < NT; nj++) {
      int c = wn + nj * 16 + lr;
      b_h[nj] = *(const short8*)&Bsh[c * LDK + lq * 8];
      b_l[nj] = *(const short8*)&Bsl[c * LDK + lq * 8];
    }
    // --- 3-term MFMA ---
#pragma unroll
    for (int mi = 0; mi < MI; mi++) {
#pragma unroll
      for (int nj = 0; nj < NT; nj++) {
        acc[mi][nj] = __builtin_amdgcn_mfma_f32_16x16x32_bf16(a_h[mi], b_l[nj], acc[mi][nj], 0, 0, 0);
        acc[mi][nj] = __builtin_amdgcn_mfma_f32_16x16x32_bf16(a_l[mi], b_h[nj], acc[mi][nj], 0, 0, 0);
        acc[mi][nj] = __builtin_amdgcn_mfma_f32_16x16x32_bf16(a_h[mi], b_h[nj], acc[mi][nj], 0, 0, 0);
      }
    }
    __syncthreads();
  }
  // --- epilogue ---
#pragma unroll
  for (int mi = 0; mi < MI; mi++) {
#pragma unroll
    for (int r = 0; r < 4; r++) {
      int row = row0 + wm + mi * 16 + lq * 4 + r;
      if (row < M) {
#pragma unroll
        for (int nj = 0; nj < NT; nj++) {
          float val = acc[mi][nj][r];
          size_t idx = (size_t)row * N + col0 + wn + nj * 16 + lr;
          C[idx] = val;
          if (Cb) Cb[idx] = __float2bfloat16(val);
        }
      }
    }
  }
}

// ---------------- attention coefficients: el/er = sum_d feat*a ----------------
__global__ void coef_kernel(const float* __restrict__ feat, const float* __restrict__ al,
                            const float* __restrict__ ar, float* __restrict__ el,
                            float* __restrict__ er, int H, int D) {
  int w = blockIdx.x * 4 + (threadIdx.x >> 6);
  int lane = threadIdx.x & 63;
  if (w >= N_NODES * H) return;
  int n = w / H, h = w % H;
  int per = D >> 6;
  const float* f   = feat + (size_t)n * H * D + (size_t)h * D;
  const float* alh = al + h * D;
  const float* arh = ar + h * D;
  float sl = 0.f, sr = 0.f;
  for (int i = 0; i < per; i++) {
    int d = lane + 64 * i;
    float fv = f[d];
    sl += fv * alh[d];
    sr += fv * arh[d];
  }
  for (int off = 32; off; off >>= 1) {
    sl += __shfl_xor(sl, off);
    sr += __shfl_xor(sr, off);
  }
  if (lane == 0) { el[w] = sl; er[w] = sr; }
}

// ---------------- layer0 aggregation: per node, 4 waves = 4 heads ----------------
// feat gather from the bf16 shadow copy (halves gather bytes); el/er stay fp32.
__global__ __launch_bounds__(256) void agg0_kernel(const int* __restrict__ rowstart,
                                                   const int* __restrict__ csr_src,
                                                   const float* __restrict__ el,
                                                   const float* __restrict__ er,
                                                   const __hip_bfloat16* __restrict__ featb,
                                                   const float* __restrict__ bias,
                                                   float* __restrict__ out) {
  int n = blockIdx.x;
  int h = threadIdx.x >> 6;
  int lane = threadIdx.x & 63;
  int start = rowstart[n];
  int deg = rowstart[n + 1] - start;
  float erd = er[n * H0 + h];
  float m = -1e30f;
  for (int i = lane; i < deg; i += 64) {
    int s = csr_src[start + i];
    m = fmaxf(m, leaky(el[s * H0 + h] + erd));
  }
  for (int off = 32; off; off >>= 1) m = fmaxf(m, __shfl_xor(m, off));
  float ssum = 0.f;
  for (int i = lane; i < deg; i += 64) {
    int s = csr_src[start + i];
    ssum += __expf(leaky(el[s * H0 + h] + erd) - m);
  }
  for (int off = 32; off; off >>= 1) ssum += __shfl_xor(ssum, off);
  float inv = (deg > 0) ? 1.f / ssum : 0.f;
  float accx = 0.f, accy = 0.f;
#pragma unroll 4
  for (int i = 0; i < deg; i++) {
    int s = csr_src[start + i];                 // wave-uniform broadcast load
    float a = __expf(leaky(el[s * H0 + h] + erd) - m) * inv;
    __hip_bfloat162 f = *(const __hip_bfloat162*)&featb[(size_t)s * (H0 * HID) + h * HID + 2 * lane];
    accx += a * __bfloat162float(f.x);
    accy += a * __bfloat162float(f.y);
  }
  int d0 = 2 * lane;
  float o0 = accx + bias[h * HID + d0];
  float o1 = accy + bias[h * HID + d0 + 1];
  o0 = o0 > 0.f ? o0 : (__expf(o0) - 1.f);   // ELU
  o1 = o1 > 0.f ? o1 : (__expf(o1) - 1.f);
  out[(size_t)n * (H0 * HID) + h * HID + d0]     = o0;
  out[(size_t)n * (H0 * HID) + h * HID + d0 + 1] = o1;
}

// ---------------- layer1 aggregation: one wave per node, D=64, fp32 ----------------
__global__ __launch_bounds__(64) void agg1_kernel(const int* __restrict__ rowstart,
                                                  const int* __restrict__ csr_src,
                                                  const float* __restrict__ el,
                                                  const float* __restrict__ er,
                                                  const float* __restrict__ feat,
                                                  const float* __restrict__ bias,
                                                  float* __restrict__ out) {
  int n = blockIdx.x;
  int lane = threadIdx.x;
  int start = rowstart[n];
  int deg = rowstart[n + 1] - start;
  float erd = er[n];
  float m = -1e30f;
  for (int i = lane; i < deg; i += 64) {
    m = fmaxf(m, leaky(el[csr_src[start + i]] + erd));
  }
  for (int off = 32; off; off >>= 1) m = fmaxf(m, __shfl_xor(m, off));
  float ssum = 0.f;
  for (int i = lane; i < deg; i += 64) {
    ssum += __expf(leaky(el[csr_src[start + i]] + erd) - m);
  }
  for (int off = 32; off; off >>= 1) ssum += __shfl_xor(ssum, off);
  float inv = (deg > 0) ? 1.f / ssum : 0.f;
  float acc = 0.f;
#pragma unroll 4
  for (int i = 0; i < deg; i++) {
    int s = csr_src[start + i];
    float a = __expf(leaky(el[s] + erd) - m) * inv;
    acc += a * feat[(size_t)s * OUT_DIM + lane];
  }
  out[(size_t)n * OUT_DIM + lane] = acc + bias[lane];
}

extern "C" void kernel_launch(void* const* d_in, const int* in_sizes, int n_in,
                              void* d_out, int out_size, void* d_ws, size_t ws_size,
                              hipStream_t stream) {
  const float* x   = (const float*)d_in[0];
  const int*   src = (const int*)d_in[1];
  const int*   dst = (const int*)d_in[2];
  const float* W1  = (const float*)d_in[3];
  const float* al1 = (const float*)d_in[4];
  const float* ar1 = (const float*)d_in[5];
  const float* b1  = (const float*)d_in[6];
  const float* W2  = (const float*)d_in[7];
  const float* al2 = (const float*)d_in[8];
  const float* ar2 = (const float*)d_in[9];
  const float* b2  = (const float*)d_in[10];

  char* ws = (char*)d_ws;
  size_t off = 0;
  auto alloc = [&](size_t bytes) -> void* {
    void* p = ws + off;
    off += (bytes + 255) & ~(size_t)255;
    return p;
  };
  int* cnt      = (int*)alloc((size_t)2 * N_NODES * 4);  // cnt + fill contiguous
  int* fill     = cnt + N_NODES;
  int* rowstart = (int*)alloc((size_t)(N_NODES + 1) * 4);
  int* csr_src  = (int*)alloc((size_t)N_EDGES * 4);
  float* feat1  = (float*)alloc((size_t)N_NODES * (H0 * HID) * 4);
  __hip_bfloat16* feat1b = (__hip_bfloat16*)alloc((size_t)N_NODES * (H0 * HID) * 2);
  float* el1    = (float*)alloc((size_t)N_NODES * H0 * 4);
  float* er1    = (float*)alloc((size_t)N_NODES * H0 * 4);
  float* h1     = (float*)alloc((size_t)N_NODES * (H0 * HID) * 4);
  float* feat2  = (float*)alloc((size_t)N_NODES * OUT_DIM * 4);
  float* el2    = (float*)alloc((size_t)N_NODES * 4);
  float* er2    = (float*)alloc((size_t)N_NODES * 4);
  (void)ws_size; (void)in_sizes; (void)n_in; (void)out_size;

  // 1) CSR build (shared by both layers)
  zero_i32<<<(2 * N_NODES + 255) / 256, 256, 0, stream>>>(cnt, 2 * N_NODES);
  hist_kernel<<<(N_EDGES + 255) / 256, 256, 0, stream>>>(dst, cnt);
  scan_kernel<<<1, 1024, 0, stream>>>(cnt, rowstart);
  fill_kernel<<<(N_EDGES + 255) / 256, 256, 0, stream>>>(src, dst, rowstart, fill, csr_src);

  // 2) layer 0: GEMM (bf16x3 MFMA, + bf16 shadow), coef, aggregate
  {
    dim3 g((H0 * HID) / 128, (N_NODES + 127) / 128);
    gemm_mfma<128, 128><<<g, 256, 0, stream>>>(x, W1, feat1, feat1b, N_NODES, H0 * HID, IN_DIM);
  }
  coef_kernel<<<(N_NODES * H0 + 3) / 4, 256, 0, stream>>>(feat1, al1, ar1, el1, er1, H0, HID);
  agg0_kernel<<<N_NODES, 256, 0, stream>>>(rowstart, csr_src, el1, er1, feat1b, b1, h1);

  // 3) layer 1 (BM=64: 313 blocks instead of 157 for better CU coverage)
  {
    dim3 g(OUT_DIM / 64, (N_NODES + 63) / 64);
    gemm_mfma<64, 64><<<g, 256, 0, stream>>>(h1, W2, feat2, (__hip_bfloat16*)nullptr, N_NODES, OUT_DIM, H0 * HID);
  }
  coef_kernel<<<(N_NODES + 3) / 4, 256, 0, stream>>>(feat2, al2, ar2, el2, er2, 1, OUT_DIM);
  agg1_kernel<<<N_NODES, 64, 0, stream>>>(rowstart, csr_src, el2, er2, feat2, b2, (float*)d_out);
}